// Round 5
// baseline (1895.504 us; speedup 1.0000x reference)
//
#include <hip/hip_runtime.h>
#include <hip/hip_bf16.h>

#define NN 100000
#define NE 1600000
#define NBN 5000
#define NCOARSE 512
#define NSB 391   // ceil(NN/256) scan blocks

// ---- ordered-uint encoding for float atomic min/max ----
__device__ __forceinline__ unsigned f2ord(float f) {
    unsigned u = __float_as_uint(f);
    return (u & 0x80000000u) ? ~u : (u | 0x80000000u);
}
__device__ __forceinline__ float ord2f(unsigned u) {
    u = (u & 0x80000000u) ? (u & 0x7FFFFFFFu) : ~u;
    return __uint_as_float(u);
}
__device__ __forceinline__ float lrelu(float x) { return x > 0.f ? x : 0.01f * x; }

// ---- mark boundary nodes ----
__global__ __launch_bounds__(256) void k_scatter(const int* __restrict__ bn, unsigned char* __restrict__ isb) {
    int i = blockIdx.x * 256 + threadIdx.x;
    if (i < NBN) isb[bn[i]] = 1;
}

// ---- embed: x = nodes_mod @ eW + eb  (wave per node, lane = feature) ----
__global__ __launch_bounds__(256) void k_embed(const float* __restrict__ nodes, const unsigned char* __restrict__ isb,
                                               const float* __restrict__ dmean, const float* __restrict__ dstd,
                                               const float* __restrict__ eW, const float* __restrict__ eb,
                                               float* __restrict__ x) {
    __shared__ float sW[448];
    __shared__ float sb[64];
    __shared__ float sm[3], sd[3];
    int t = threadIdx.x;
    for (int i = t; i < 448; i += 256) sW[i] = eW[i];
    if (t < 64) sb[t] = eb[t];
    if (t < 3) { sm[t] = dmean[t]; sd[t] = dstd[t]; }
    __syncthreads();
    int lane = t & 63, wv = t >> 6;
    int w = blockIdx.x * 4 + wv, nw = gridDim.x * 4;
    for (int n = w; n < NN; n += nw) {
        float row[7];
#pragma unroll
        for (int k = 0; k < 7; k++) row[k] = nodes[n * 7 + k];
        if (isb[n]) {
#pragma unroll
            for (int k = 0; k < 3; k++) row[3 + k] = (row[3 + k] - sm[k]) / sd[k];
        }
        float acc = sb[lane];
#pragma unroll
        for (int k = 0; k < 7; k++) acc += row[k] * sW[k * 64 + lane];
        x[n * 64 + lane] = acc;
    }
}

// ---- coords min/max (ordered-uint atomics) ----
__global__ __launch_bounds__(256) void k_minmax(const float* __restrict__ nodes, unsigned* __restrict__ mn_ord,
                                                unsigned* __restrict__ mx_ord) {
    int tid = blockIdx.x * 256 + threadIdx.x;
    int stride = gridDim.x * 256;
    float mn[3] = {INFINITY, INFINITY, INFINITY};
    float mx[3] = {-INFINITY, -INFINITY, -INFINITY};
    for (int n = tid; n < NN; n += stride) {
#pragma unroll
        for (int k = 0; k < 3; k++) {
            float c = nodes[n * 7 + k];
            mn[k] = fminf(mn[k], c);
            mx[k] = fmaxf(mx[k], c);
        }
    }
#pragma unroll
    for (int off = 32; off; off >>= 1) {
#pragma unroll
        for (int k = 0; k < 3; k++) {
            mn[k] = fminf(mn[k], __shfl_down(mn[k], off));
            mx[k] = fmaxf(mx[k], __shfl_down(mx[k], off));
        }
    }
    if ((threadIdx.x & 63) == 0) {
#pragma unroll
        for (int k = 0; k < 3; k++) {
            atomicMin(&mn_ord[k], f2ord(mn[k]));
            atomicMax(&mx_ord[k], f2ord(mx[k]));
        }
    }
}

// ---- voxel block id per node ----
__global__ __launch_bounds__(256) void k_bid(const float* __restrict__ nodes, const unsigned* __restrict__ mn_ord,
                                             const unsigned* __restrict__ mx_ord, int* __restrict__ bid) {
    int n = blockIdx.x * 256 + threadIdx.x;
    if (n >= NN) return;
    int g[3];
#pragma unroll
    for (int k = 0; k < 3; k++) {
        float mn = ord2f(mn_ord[k]), mx = ord2f(mx_ord[k]);
        float cell = (mx - mn) / 8.0f;
        int gi = (int)floorf((nodes[n * 7 + k] - mn) / cell);
        gi = gi < 0 ? 0 : (gi > 7 ? 7 : gi);
        g[k] = gi;
    }
    bid[n] = g[0] * 64 + g[1] * 8 + g[2];
}

// ---- generic: h = x@W; a_s = h·A[:64]; a_r = h·A[64:]  (wave per row) ----
__global__ __launch_bounds__(256) void k_mm(const float* __restrict__ x, const float* __restrict__ W,
                                            const float* __restrict__ A, float* __restrict__ h,
                                            float* __restrict__ as_, float* __restrict__ ar_, int nrow) {
    __shared__ float sW[4096];
    __shared__ float sA[128];
    int t = threadIdx.x;
    for (int i = t; i < 4096; i += 256) sW[i] = W[i];
    if (t < 128) sA[t] = A[t];
    __syncthreads();
    int lane = t & 63, wv = t >> 6;
    int w = blockIdx.x * 4 + wv, nw = gridDim.x * 4;
    for (int n = w; n < nrow; n += nw) {
        const float* xr = x + (size_t)n * 64;
        float acc = 0.f;
#pragma unroll
        for (int k = 0; k < 64; k++) acc += xr[k] * sW[k * 64 + lane];
        h[(size_t)n * 64 + lane] = acc;
        float va = acc * sA[lane], vr = acc * sA[64 + lane];
#pragma unroll
        for (int off = 32; off; off >>= 1) {
            va += __shfl_down(va, off);
            vr += __shfl_down(vr, off);
        }
        if (lane == 0) { as_[n] = va; ar_[n] = vr; }
    }
}

// ---- CSR build: degree histogram ----
__global__ __launch_bounds__(256) void k_deg(const int* __restrict__ re, unsigned* __restrict__ deg) {
    int e = blockIdx.x * 256 + threadIdx.x;
    if (e < NE) atomicAdd(&deg[re[e]], 1u);
}

// ---- scan step 1: per-block exclusive scan + block totals ----
__global__ __launch_bounds__(256) void k_scan1(const unsigned* __restrict__ deg, unsigned* __restrict__ rowptr,
                                               unsigned* __restrict__ partial) {
    __shared__ unsigned s[256];
    int t = threadIdx.x, i = blockIdx.x * 256 + t;
    unsigned v = (i < NN) ? deg[i] : 0u;
    s[t] = v;
    __syncthreads();
    for (int off = 1; off < 256; off <<= 1) {
        unsigned u = (t >= off) ? s[t - off] : 0u;
        __syncthreads();
        s[t] += u;
        __syncthreads();
    }
    if (i < NN) rowptr[i] = s[t] - v;
    if (t == 255) partial[blockIdx.x] = s[255];
}

// ---- scan step 2: scan the block totals (one block) ----
__global__ __launch_bounds__(512) void k_scan2(unsigned* __restrict__ partial) {
    __shared__ unsigned s[512];
    int t = threadIdx.x;
    unsigned v = (t < NSB) ? partial[t] : 0u;
    s[t] = v;
    __syncthreads();
    for (int off = 1; off < 512; off <<= 1) {
        unsigned u = (t >= off) ? s[t - off] : 0u;
        __syncthreads();
        s[t] += u;
        __syncthreads();
    }
    if (t < NSB) partial[t] = s[t] - v;   // exclusive
}

// ---- scan step 3: add block offsets; init cursor; write sentinel ----
__global__ __launch_bounds__(256) void k_scan3(unsigned* __restrict__ rowptr, const unsigned* __restrict__ partial,
                                               unsigned* __restrict__ cursor) {
    int t = threadIdx.x, i = blockIdx.x * 256 + t;
    if (i < NN) {
        unsigned r = rowptr[i] + partial[blockIdx.x];
        rowptr[i] = r;
        cursor[i] = r;
    }
    if (i == 0) rowptr[NN] = NE;
}

// ---- CSR fill: scatter senders into receiver segments ----
__global__ __launch_bounds__(256) void k_fill(const int* __restrict__ se, const int* __restrict__ re,
                                              unsigned* __restrict__ cursor, int* __restrict__ csr_s) {
    int e = blockIdx.x * 256 + threadIdx.x;
    if (e >= NE) return;
    unsigned pos = atomicAdd(&cursor[re[e]], 1u);
    csr_s[pos] = se[e];
}

// ---- fused fine GAT: online softmax + aggregate + graphnorm stats ----
// wave per receiver; 4 groups of 16 lanes, one edge per group per iter, float4 rows
__global__ __launch_bounds__(256) void k_gat1(const unsigned* __restrict__ rowptr, const int* __restrict__ csr_s,
                                              const float* __restrict__ as_, const float* __restrict__ ar_,
                                              const float* __restrict__ h, float* __restrict__ o_raw,
                                              float* __restrict__ colsum, float* __restrict__ colsq) {
    __shared__ float sA[4][64], sQ[4][64];
    int t = threadIdx.x, lane = t & 63, wv = t >> 6;
    int r = blockIdx.x * 4 + wv;
    int g = lane >> 4, fl = lane & 15;
    int p0 = rowptr[r], p1 = rowptr[r + 1];
    float arj = ar_[r];
    float m = -INFINITY, ss = 0.f;
    float a0 = 0.f, a1 = 0.f, a2 = 0.f, a3 = 0.f;
    for (int p = p0 + g; p < p1; p += 4) {
        int s = csr_s[p];
        float sc = lrelu(as_[s] + arj);
        const float4 hv = *(const float4*)(h + (size_t)s * 64 + fl * 4);
        float newm = fmaxf(m, sc);
        float scale = __expf(m - newm);   // m=-inf,newm finite -> 0
        float w = __expf(sc - newm);
        ss = ss * scale + w;
        a0 = a0 * scale + w * hv.x;
        a1 = a1 * scale + w * hv.y;
        a2 = a2 * scale + w * hv.z;
        a3 = a3 * scale + w * hv.w;
        m = newm;
    }
    // merge (m, ss, acc) across the 4 groups
#pragma unroll
    for (int off = 16; off < 64; off <<= 1) {
        float m2 = __shfl_xor(m, off);
        float ss2 = __shfl_xor(ss, off);
        float b0 = __shfl_xor(a0, off), b1 = __shfl_xor(a1, off);
        float b2 = __shfl_xor(a2, off), b3 = __shfl_xor(a3, off);
        float M = fmaxf(m, m2);
        float e1 = (M == -INFINITY) ? 0.f : __expf(m - M);
        float e2 = (M == -INFINITY) ? 0.f : __expf(m2 - M);
        ss = ss * e1 + ss2 * e2;
        a0 = a0 * e1 + b0 * e2;
        a1 = a1 * e1 + b1 * e2;
        a2 = a2 * e1 + b2 * e2;
        a3 = a3 * e1 + b3 * e2;
        m = M;
    }
    float inv = ss > 0.f ? 1.f / ss : 0.f;
    float v0 = a0 * inv, v1 = a1 * inv, v2 = a2 * inv, v3 = a3 * inv;
    if (g == 0) {
        float4 v = make_float4(v0, v1, v2, v3);
        *(float4*)(o_raw + (size_t)r * 64 + fl * 4) = v;
        sA[wv][fl * 4 + 0] = v0; sQ[wv][fl * 4 + 0] = v0 * v0;
        sA[wv][fl * 4 + 1] = v1; sQ[wv][fl * 4 + 1] = v1 * v1;
        sA[wv][fl * 4 + 2] = v2; sQ[wv][fl * 4 + 2] = v2 * v2;
        sA[wv][fl * 4 + 3] = v3; sQ[wv][fl * 4 + 3] = v3 * v3;
    }
    __syncthreads();
    if (t < 64) {
        float a = sA[0][t] + sA[1][t] + sA[2][t] + sA[3][t];
        float q = sQ[0][t] + sQ[1][t] + sQ[2][t] + sQ[3][t];
        unsafeAtomicAdd(&colsum[t], a);
        unsafeAtomicAdd(&colsq[t], q);
    }
}

__global__ void k_meanvar(const float* __restrict__ colsum, const float* __restrict__ colsq, float* __restrict__ mr) {
    int t = threadIdx.x;
    if (t < 64) {
        float mean = colsum[t] / (float)NN;
        float var = colsq[t] / (float)NN - mean * mean;
        mr[t] = mean;
        mr[64 + t] = rsqrtf(var + 1e-5f);
    }
}

// ---- graphnorm + silu + res1; fused cnodes/segment-size accumulation ----
__global__ __launch_bounds__(256) void k_apply(const float* __restrict__ o_raw, const float* __restrict__ res1,
                                               const float* __restrict__ gamma, const float* __restrict__ beta,
                                               const float* __restrict__ mr, const int* __restrict__ bid,
                                               float* __restrict__ x1, float* __restrict__ cn,
                                               float* __restrict__ bsize) {
    int t = threadIdx.x, lane = t & 63;
    int n = blockIdx.x * 4 + (t >> 6);
    if (n >= NN) return;
    float v = o_raw[(size_t)n * 64 + lane];
    float y = gamma[lane] * (v - mr[lane]) * mr[64 + lane] + beta[lane];
    float s = y / (1.f + __expf(-y));
    float o = s + res1[(size_t)n * 64 + lane];
    x1[(size_t)n * 64 + lane] = o;
    int b = bid[n];
    unsafeAtomicAdd(&cn[b * 64 + lane], o);
    if (lane == 0) unsafeAtomicAdd(&bsize[b], 1.f);
}

// ---- coarse edge-count matrix ----
__global__ __launch_bounds__(256) void k_cnt(const int* __restrict__ se, const int* __restrict__ re,
                                             const int* __restrict__ bid, unsigned* __restrict__ cnt) {
    int e = blockIdx.x * 256 + threadIdx.x;
    if (e >= NE) return;
    atomicAdd(&cnt[bid[se[e]] * NCOARSE + bid[re[e]]], 1u);
}

// ---- cnodes scale: x2 = cn / sqrt(size + 1e-10) ----
__global__ __launch_bounds__(256) void k_cnscale(const float* __restrict__ cn, const float* __restrict__ bsize,
                                                 float* __restrict__ x2) {
    int t = threadIdx.x, lane = t & 63;
    int b = blockIdx.x * 4 + (t >> 6);
    if (b >= NCOARSE) return;
    x2[b * 64 + lane] = cn[b * 64 + lane] / sqrtf(bsize[b] + 1e-10f);
}

// ---- dense coarse GAT via count matrix (wave per receiver j) ----
__global__ __launch_bounds__(256) void k_cgat(const float* __restrict__ h, const float* __restrict__ as_,
                                              const float* __restrict__ ar_, const unsigned* __restrict__ cnt,
                                              float* __restrict__ g) {
    __shared__ float sa[NCOARSE];
    int t = threadIdx.x;
    for (int i = t; i < NCOARSE; i += 256) sa[i] = as_[i];
    __syncthreads();
    int lane = t & 63, wv = t >> 6;
    int j = blockIdx.x * 4 + wv;
    float arj = ar_[j];
    float m = -INFINITY;
    for (int i = 0; i < NCOARSE; i++) {
        if (cnt[i * NCOARSE + j]) m = fmaxf(m, lrelu(sa[i] + arj));
    }
    float ss = 0.f, acc = 0.f;
    for (int i = 0; i < NCOARSE; i++) {
        unsigned c = cnt[i * NCOARSE + j];
        if (c) {
            float w = (float)c * __expf(lrelu(sa[i] + arj) - m);
            ss += w;
            acc += w * h[i * 64 + lane];
        }
    }
    g[j * 64 + lane] = ss > 0.f ? acc / ss : 0.f;
}

// ---- coarse graphnorm + silu + residual (wave per feature) ----
__global__ __launch_bounds__(64) void k_cnorm(const float* __restrict__ gin, const float* __restrict__ gamma,
                                              const float* __restrict__ beta, const float* __restrict__ res,
                                              float* __restrict__ xout) {
    int f = blockIdx.x, lane = threadIdx.x;
    float v[8];
    float s = 0.f, q = 0.f;
#pragma unroll
    for (int k = 0; k < 8; k++) {
        v[k] = gin[(lane + 64 * k) * 64 + f];
        s += v[k];
        q += v[k] * v[k];
    }
#pragma unroll
    for (int off = 32; off; off >>= 1) {
        s += __shfl_down(s, off);
        q += __shfl_down(q, off);
    }
    s = __shfl(s, 0);
    q = __shfl(q, 0);
    float mean = s / 512.f, var = q / 512.f - mean * mean, rstd = rsqrtf(var + 1e-5f);
    float gf = gamma[f], bf = beta[f];
#pragma unroll
    for (int k = 0; k < 8; k++) {
        float y = gf * (v[k] - mean) * rstd + bf;
        float si = y / (1.f + __expf(-y));
        int idx = (lane + 64 * k) * 64 + f;
        xout[idx] = si + res[idx];
    }
}

// ---- final: out = sum_n sum_f (g3+x3)[n][f] * dW[f] + db ----
__global__ __launch_bounds__(256) void k_final(const float* __restrict__ g3, const float* __restrict__ x3,
                                               const float* __restrict__ dW, const float* __restrict__ db,
                                               float* __restrict__ out) {
    __shared__ float l[4];
    int t = threadIdx.x;
    float p = 0.f;
    for (int idx = t; idx < NCOARSE * 64; idx += 256) p += (g3[idx] + x3[idx]) * dW[idx & 63];
#pragma unroll
    for (int off = 32; off; off >>= 1) p += __shfl_down(p, off);
    if ((t & 63) == 0) l[t >> 6] = p;
    __syncthreads();
    if (t == 0) out[0] = l[0] + l[1] + l[2] + l[3] + db[0];
}

extern "C" void kernel_launch(void* const* d_in, const int* in_sizes, int n_in,
                              void* d_out, int out_size, void* d_ws, size_t ws_size,
                              hipStream_t stream) {
    const float* nodes = (const float*)d_in[0];
    const int* senders = (const int*)d_in[1];
    const int* receivers = (const int*)d_in[2];
    const int* bnodes = (const int*)d_in[3];
    const float* dmean = (const float*)d_in[4];
    const float* dstd = (const float*)d_in[5];
    const float* eW = (const float*)d_in[6];
    const float* eb = (const float*)d_in[7];
    const float* W1 = (const float*)d_in[8];
    const float* A1 = (const float*)d_in[9];
    const float* gamma1 = (const float*)d_in[10];
    const float* beta1 = (const float*)d_in[11];
    const float* W2 = (const float*)d_in[12];
    const float* A2 = (const float*)d_in[13];
    const float* gamma2 = (const float*)d_in[14];
    const float* beta2 = (const float*)d_in[15];
    const float* W3 = (const float*)d_in[16];
    const float* A3 = (const float*)d_in[17];
    const float* dW = (const float*)d_in[18];
    const float* db = (const float*)d_in[19];
    float* out = (float*)d_out;

    char* p = (char*)d_ws;
    auto alloc = [&](size_t b) { char* r = p; p += (b + 255) & ~(size_t)255; return r; };
    float* x_emb = (float*)alloc((size_t)NN * 64 * 4);   // res1
    float* h1 = (float*)alloc((size_t)NN * 64 * 4);      // reused as x1 after gat1
    float* o_raw = (float*)alloc((size_t)NN * 64 * 4);
    float* as1 = (float*)alloc(NN * 4);
    float* ar1 = (float*)alloc(NN * 4);
    int* bid = (int*)alloc(NN * 4);
    unsigned char* isb = (unsigned char*)alloc(NN);
    float* colsum = (float*)alloc(64 * 4);
    float* colsq = (float*)alloc(64 * 4);
    float* mr = (float*)alloc(128 * 4);
    unsigned* mn_ord = (unsigned*)alloc(3 * 4);
    unsigned* mx_ord = (unsigned*)alloc(3 * 4);
    unsigned* cnt = (unsigned*)alloc((size_t)NCOARSE * NCOARSE * 4);
    float* cn = (float*)alloc(NCOARSE * 64 * 4);
    float* bsize = (float*)alloc(NCOARSE * 4);
    float* x2 = (float*)alloc(NCOARSE * 64 * 4);   // res2
    float* h2 = (float*)alloc(NCOARSE * 64 * 4);
    float* as2 = (float*)alloc(NCOARSE * 4);
    float* ar2 = (float*)alloc(NCOARSE * 4);
    float* gat2 = (float*)alloc(NCOARSE * 64 * 4);
    float* x3 = (float*)alloc(NCOARSE * 64 * 4);   // res3
    float* h3 = (float*)alloc(NCOARSE * 64 * 4);
    float* as3 = (float*)alloc(NCOARSE * 4);
    float* ar3 = (float*)alloc(NCOARSE * 4);
    float* gat3 = (float*)alloc(NCOARSE * 64 * 4);
    unsigned* deg = (unsigned*)alloc(NN * 4);
    unsigned* rowptr = (unsigned*)alloc((NN + 1) * 4);
    unsigned* cursor = (unsigned*)alloc(NN * 4);
    unsigned* partial = (unsigned*)alloc(512 * 4);
    int* csr_s = (int*)alloc((size_t)NE * 4);

    hipMemsetAsync(isb, 0, NN, stream);
    hipMemsetAsync(colsum, 0, 64 * 4, stream);
    hipMemsetAsync(colsq, 0, 64 * 4, stream);
    hipMemsetAsync(mn_ord, 0xFF, 12, stream);
    hipMemsetAsync(mx_ord, 0, 12, stream);
    hipMemsetAsync(cnt, 0, (size_t)NCOARSE * NCOARSE * 4, stream);
    hipMemsetAsync(cn, 0, NCOARSE * 64 * 4, stream);
    hipMemsetAsync(bsize, 0, NCOARSE * 4, stream);
    hipMemsetAsync(deg, 0, NN * 4, stream);

    k_scatter<<<(NBN + 255) / 256, 256, 0, stream>>>(bnodes, isb);
    k_embed<<<2048, 256, 0, stream>>>(nodes, isb, dmean, dstd, eW, eb, x_emb);
    k_minmax<<<512, 256, 0, stream>>>(nodes, mn_ord, mx_ord);
    k_bid<<<(NN + 255) / 256, 256, 0, stream>>>(nodes, mn_ord, mx_ord, bid);
    k_deg<<<(NE + 255) / 256, 256, 0, stream>>>(receivers, deg);
    k_scan1<<<NSB, 256, 0, stream>>>(deg, rowptr, partial);
    k_scan2<<<1, 512, 0, stream>>>(partial);
    k_scan3<<<NSB, 256, 0, stream>>>(rowptr, partial, cursor);
    k_fill<<<(NE + 255) / 256, 256, 0, stream>>>(senders, receivers, cursor, csr_s);
    k_mm<<<2048, 256, 0, stream>>>(x_emb, W1, A1, h1, as1, ar1, NN);
    k_gat1<<<NN / 4, 256, 0, stream>>>(rowptr, csr_s, as1, ar1, h1, o_raw, colsum, colsq);
    k_meanvar<<<1, 64, 0, stream>>>(colsum, colsq, mr);
    k_apply<<<NN / 4, 256, 0, stream>>>(o_raw, x_emb, gamma1, beta1, mr, bid, h1, cn, bsize);
    k_cnt<<<(NE + 255) / 256, 256, 0, stream>>>(senders, receivers, bid, cnt);
    k_cnscale<<<NCOARSE / 4, 256, 0, stream>>>(cn, bsize, x2);
    k_mm<<<NCOARSE / 4, 256, 0, stream>>>(x2, W2, A2, h2, as2, ar2, NCOARSE);
    k_cgat<<<NCOARSE / 4, 256, 0, stream>>>(h2, as2, ar2, cnt, gat2);
    k_cnorm<<<64, 64, 0, stream>>>(gat2, gamma2, beta2, x2, x3);
    k_mm<<<NCOARSE / 4, 256, 0, stream>>>(x3, W3, A3, h3, as3, ar3, NCOARSE);
    k_cgat<<<NCOARSE / 4, 256, 0, stream>>>(h3, as3, ar3, cnt, gat3);
    k_final<<<1, 256, 0, stream>>>(gat3, x3, dW, db, out);
}

// Round 6
// 1367.286 us; speedup vs baseline: 1.3863x; 1.3863x over previous
//
#include <hip/hip_runtime.h>
#include <hip/hip_bf16.h>

#define NN 100000
#define NE 1600000
#define NBN 5000
#define NCOARSE 512
#define NSB 391   // ceil(NN/256) scan blocks

// ---- ordered-uint encoding for float atomic min/max ----
__device__ __forceinline__ unsigned f2ord(float f) {
    unsigned u = __float_as_uint(f);
    return (u & 0x80000000u) ? ~u : (u | 0x80000000u);
}
__device__ __forceinline__ float ord2f(unsigned u) {
    u = (u & 0x80000000u) ? (u & 0x7FFFFFFFu) : ~u;
    return __uint_as_float(u);
}
__device__ __forceinline__ float lrelu(float x) { return x > 0.f ? x : 0.01f * x; }

// ---- mark boundary nodes ----
__global__ __launch_bounds__(256) void k_scatter(const int* __restrict__ bn, unsigned char* __restrict__ isb) {
    int i = blockIdx.x * 256 + threadIdx.x;
    if (i < NBN) isb[bn[i]] = 1;
}

// ---- embed: x = nodes_mod @ eW + eb  (wave per node, lane = feature) ----
__global__ __launch_bounds__(256) void k_embed(const float* __restrict__ nodes, const unsigned char* __restrict__ isb,
                                               const float* __restrict__ dmean, const float* __restrict__ dstd,
                                               const float* __restrict__ eW, const float* __restrict__ eb,
                                               float* __restrict__ x) {
    __shared__ float sW[448];
    __shared__ float sb[64];
    __shared__ float sm[3], sd[3];
    int t = threadIdx.x;
    for (int i = t; i < 448; i += 256) sW[i] = eW[i];
    if (t < 64) sb[t] = eb[t];
    if (t < 3) { sm[t] = dmean[t]; sd[t] = dstd[t]; }
    __syncthreads();
    int lane = t & 63, wv = t >> 6;
    int w = blockIdx.x * 4 + wv, nw = gridDim.x * 4;
    for (int n = w; n < NN; n += nw) {
        float row[7];
#pragma unroll
        for (int k = 0; k < 7; k++) row[k] = nodes[n * 7 + k];
        if (isb[n]) {
#pragma unroll
            for (int k = 0; k < 3; k++) row[3 + k] = (row[3 + k] - sm[k]) / sd[k];
        }
        float acc = sb[lane];
#pragma unroll
        for (int k = 0; k < 7; k++) acc += row[k] * sW[k * 64 + lane];
        x[n * 64 + lane] = acc;
    }
}

// ---- coords min/max (ordered-uint atomics) ----
__global__ __launch_bounds__(256) void k_minmax(const float* __restrict__ nodes, unsigned* __restrict__ mn_ord,
                                                unsigned* __restrict__ mx_ord) {
    int tid = blockIdx.x * 256 + threadIdx.x;
    int stride = gridDim.x * 256;
    float mn[3] = {INFINITY, INFINITY, INFINITY};
    float mx[3] = {-INFINITY, -INFINITY, -INFINITY};
    for (int n = tid; n < NN; n += stride) {
#pragma unroll
        for (int k = 0; k < 3; k++) {
            float c = nodes[n * 7 + k];
            mn[k] = fminf(mn[k], c);
            mx[k] = fmaxf(mx[k], c);
        }
    }
#pragma unroll
    for (int off = 32; off; off >>= 1) {
#pragma unroll
        for (int k = 0; k < 3; k++) {
            mn[k] = fminf(mn[k], __shfl_down(mn[k], off));
            mx[k] = fmaxf(mx[k], __shfl_down(mx[k], off));
        }
    }
    if ((threadIdx.x & 63) == 0) {
#pragma unroll
        for (int k = 0; k < 3; k++) {
            atomicMin(&mn_ord[k], f2ord(mn[k]));
            atomicMax(&mx_ord[k], f2ord(mx[k]));
        }
    }
}

// ---- voxel block id per node ----
__global__ __launch_bounds__(256) void k_bid(const float* __restrict__ nodes, const unsigned* __restrict__ mn_ord,
                                             const unsigned* __restrict__ mx_ord, int* __restrict__ bid) {
    int n = blockIdx.x * 256 + threadIdx.x;
    if (n >= NN) return;
    int g[3];
#pragma unroll
    for (int k = 0; k < 3; k++) {
        float mn = ord2f(mn_ord[k]), mx = ord2f(mx_ord[k]);
        float cell = (mx - mn) / 8.0f;
        int gi = (int)floorf((nodes[n * 7 + k] - mn) / cell);
        gi = gi < 0 ? 0 : (gi > 7 ? 7 : gi);
        g[k] = gi;
    }
    bid[n] = g[0] * 64 + g[1] * 8 + g[2];
}

// ---- generic: h = x@W; a_s = h·A[:64]; a_r = h·A[64:]  (wave per row) ----
__global__ __launch_bounds__(256) void k_mm(const float* __restrict__ x, const float* __restrict__ W,
                                            const float* __restrict__ A, float* __restrict__ h,
                                            float* __restrict__ as_, float* __restrict__ ar_, int nrow) {
    __shared__ float sW[4096];
    __shared__ float sA[128];
    int t = threadIdx.x;
    for (int i = t; i < 4096; i += 256) sW[i] = W[i];
    if (t < 128) sA[t] = A[t];
    __syncthreads();
    int lane = t & 63, wv = t >> 6;
    int w = blockIdx.x * 4 + wv, nw = gridDim.x * 4;
    for (int n = w; n < nrow; n += nw) {
        const float* xr = x + (size_t)n * 64;
        float acc = 0.f;
#pragma unroll
        for (int k = 0; k < 64; k++) acc += xr[k] * sW[k * 64 + lane];
        h[(size_t)n * 64 + lane] = acc;
        float va = acc * sA[lane], vr = acc * sA[64 + lane];
#pragma unroll
        for (int off = 32; off; off >>= 1) {
            va += __shfl_down(va, off);
            vr += __shfl_down(vr, off);
        }
        if (lane == 0) { as_[n] = va; ar_[n] = vr; }
    }
}

// ---- CSR build: degree histogram ----
__global__ __launch_bounds__(256) void k_deg(const int* __restrict__ re, unsigned* __restrict__ deg) {
    int e = blockIdx.x * 256 + threadIdx.x;
    if (e < NE) atomicAdd(&deg[re[e]], 1u);
}

// ---- scan step 1: per-block exclusive scan + block totals ----
__global__ __launch_bounds__(256) void k_scan1(const unsigned* __restrict__ deg, unsigned* __restrict__ rowptr,
                                               unsigned* __restrict__ partial) {
    __shared__ unsigned s[256];
    int t = threadIdx.x, i = blockIdx.x * 256 + t;
    unsigned v = (i < NN) ? deg[i] : 0u;
    s[t] = v;
    __syncthreads();
    for (int off = 1; off < 256; off <<= 1) {
        unsigned u = (t >= off) ? s[t - off] : 0u;
        __syncthreads();
        s[t] += u;
        __syncthreads();
    }
    if (i < NN) rowptr[i] = s[t] - v;
    if (t == 255) partial[blockIdx.x] = s[255];
}

// ---- scan step 2: scan the block totals (one block) ----
__global__ __launch_bounds__(512) void k_scan2(unsigned* __restrict__ partial) {
    __shared__ unsigned s[512];
    int t = threadIdx.x;
    unsigned v = (t < NSB) ? partial[t] : 0u;
    s[t] = v;
    __syncthreads();
    for (int off = 1; off < 512; off <<= 1) {
        unsigned u = (t >= off) ? s[t - off] : 0u;
        __syncthreads();
        s[t] += u;
        __syncthreads();
    }
    if (t < NSB) partial[t] = s[t] - v;   // exclusive
}

// ---- scan step 3: add block offsets; init cursor; write sentinel ----
__global__ __launch_bounds__(256) void k_scan3(unsigned* __restrict__ rowptr, const unsigned* __restrict__ partial,
                                               unsigned* __restrict__ cursor) {
    int t = threadIdx.x, i = blockIdx.x * 256 + t;
    if (i < NN) {
        unsigned r = rowptr[i] + partial[blockIdx.x];
        rowptr[i] = r;
        cursor[i] = r;
    }
    if (i == 0) rowptr[NN] = NE;
}

// ---- CSR fill: scatter senders into receiver segments ----
__global__ __launch_bounds__(256) void k_fill(const int* __restrict__ se, const int* __restrict__ re,
                                              unsigned* __restrict__ cursor, int* __restrict__ csr_s) {
    int e = blockIdx.x * 256 + threadIdx.x;
    if (e >= NE) return;
    unsigned pos = atomicAdd(&cursor[re[e]], 1u);
    csr_s[pos] = se[e];
}

// ---- fused fine GAT: online softmax + aggregate (NO stats tail) ----
// wave per receiver; 4 groups of 16 lanes, one edge per group per iter, float4 rows
// index-prefetch breaks the csr_s->gather dependent chain across iterations
__global__ __launch_bounds__(256) void k_gat1(const unsigned* __restrict__ rowptr, const int* __restrict__ csr_s,
                                              const float* __restrict__ as_, const float* __restrict__ ar_,
                                              const float* __restrict__ h, float* __restrict__ o_raw) {
    int t = threadIdx.x, lane = t & 63, wv = t >> 6;
    int r = blockIdx.x * 4 + wv;
    int g = lane >> 4, fl = lane & 15;
    int p0 = rowptr[r], p1 = rowptr[r + 1];
    float arj = ar_[r];
    float m = -INFINITY, ss = 0.f;
    float a0 = 0.f, a1 = 0.f, a2 = 0.f, a3 = 0.f;
    int p = p0 + g;
    int s = (p < p1) ? csr_s[p] : 0;
    while (p < p1) {
        int pn = p + 4;
        int sn = (pn < p1) ? csr_s[pn] : 0;     // prefetch next index
        float sc = lrelu(as_[s] + arj);
        const float4 hv = *(const float4*)(h + (size_t)s * 64 + fl * 4);
        float newm = fmaxf(m, sc);
        float scale = __expf(m - newm);   // m=-inf,newm finite -> 0
        float w = __expf(sc - newm);
        ss = ss * scale + w;
        a0 = a0 * scale + w * hv.x;
        a1 = a1 * scale + w * hv.y;
        a2 = a2 * scale + w * hv.z;
        a3 = a3 * scale + w * hv.w;
        m = newm;
        p = pn;
        s = sn;
    }
    // merge (m, ss, acc) across the 4 groups
#pragma unroll
    for (int off = 16; off < 64; off <<= 1) {
        float m2 = __shfl_xor(m, off);
        float ss2 = __shfl_xor(ss, off);
        float b0 = __shfl_xor(a0, off), b1 = __shfl_xor(a1, off);
        float b2 = __shfl_xor(a2, off), b3 = __shfl_xor(a3, off);
        float M = fmaxf(m, m2);
        float e1 = (M == -INFINITY) ? 0.f : __expf(m - M);
        float e2 = (M == -INFINITY) ? 0.f : __expf(m2 - M);
        ss = ss * e1 + ss2 * e2;
        a0 = a0 * e1 + b0 * e2;
        a1 = a1 * e1 + b1 * e2;
        a2 = a2 * e1 + b2 * e2;
        a3 = a3 * e1 + b3 * e2;
        m = M;
    }
    if (g == 0) {
        float inv = ss > 0.f ? 1.f / ss : 0.f;
        float4 v = make_float4(a0 * inv, a1 * inv, a2 * inv, a3 * inv);
        *(float4*)(o_raw + (size_t)r * 64 + fl * 4) = v;
    }
}

// ---- column stats over o_raw (512-block grid -> only 65k atomics) ----
__global__ __launch_bounds__(256) void k_stats2(const float* __restrict__ o_raw,
                                                float* __restrict__ colsum, float* __restrict__ colsq) {
    __shared__ float l1[4][64], l2[4][64];
    int t = threadIdx.x, lane = t & 63, wv = t >> 6;
    int w = blockIdx.x * 4 + wv, nw = gridDim.x * 4;
    float cs = 0.f, cq = 0.f;
    for (int n = w; n < NN; n += nw) {
        float v = o_raw[(size_t)n * 64 + lane];
        cs += v;
        cq += v * v;
    }
    l1[wv][lane] = cs;
    l2[wv][lane] = cq;
    __syncthreads();
    if (wv == 0) {
        float a = l1[0][lane] + l1[1][lane] + l1[2][lane] + l1[3][lane];
        float b = l2[0][lane] + l2[1][lane] + l2[2][lane] + l2[3][lane];
        unsafeAtomicAdd(&colsum[lane], a);
        unsafeAtomicAdd(&colsq[lane], b);
    }
}

__global__ void k_meanvar(const float* __restrict__ colsum, const float* __restrict__ colsq, float* __restrict__ mr) {
    int t = threadIdx.x;
    if (t < 64) {
        float mean = colsum[t] / (float)NN;
        float var = colsq[t] / (float)NN - mean * mean;
        mr[t] = mean;
        mr[64 + t] = rsqrtf(var + 1e-5f);
    }
}

// ---- graphnorm + silu + res1; fused cnodes/segment-size accumulation ----
__global__ __launch_bounds__(256) void k_apply(const float* __restrict__ o_raw, const float* __restrict__ res1,
                                               const float* __restrict__ gamma, const float* __restrict__ beta,
                                               const float* __restrict__ mr, const int* __restrict__ bid,
                                               float* __restrict__ x1, float* __restrict__ cn,
                                               float* __restrict__ bsize) {
    int t = threadIdx.x, lane = t & 63;
    int n = blockIdx.x * 4 + (t >> 6);
    if (n >= NN) return;
    float v = o_raw[(size_t)n * 64 + lane];
    float y = gamma[lane] * (v - mr[lane]) * mr[64 + lane] + beta[lane];
    float s = y / (1.f + __expf(-y));
    float o = s + res1[(size_t)n * 64 + lane];
    x1[(size_t)n * 64 + lane] = o;
    int b = bid[n];
    unsafeAtomicAdd(&cn[b * 64 + lane], o);
    if (lane == 0) unsafeAtomicAdd(&bsize[b], 1.f);
}

// ---- coarse edge-count matrix ----
__global__ __launch_bounds__(256) void k_cnt(const int* __restrict__ se, const int* __restrict__ re,
                                             const int* __restrict__ bid, unsigned* __restrict__ cnt) {
    int e = blockIdx.x * 256 + threadIdx.x;
    if (e >= NE) return;
    atomicAdd(&cnt[bid[se[e]] * NCOARSE + bid[re[e]]], 1u);
}

// ---- cnodes scale: x2 = cn / sqrt(size + 1e-10) ----
__global__ __launch_bounds__(256) void k_cnscale(const float* __restrict__ cn, const float* __restrict__ bsize,
                                                 float* __restrict__ x2) {
    int t = threadIdx.x, lane = t & 63;
    int b = blockIdx.x * 4 + (t >> 6);
    if (b >= NCOARSE) return;
    x2[b * 64 + lane] = cn[b * 64 + lane] / sqrtf(bsize[b] + 1e-10f);
}

// ---- dense coarse GAT via count matrix (wave per receiver j) ----
__global__ __launch_bounds__(256) void k_cgat(const float* __restrict__ h, const float* __restrict__ as_,
                                              const float* __restrict__ ar_, const unsigned* __restrict__ cnt,
                                              float* __restrict__ g) {
    __shared__ float sa[NCOARSE];
    int t = threadIdx.x;
    for (int i = t; i < NCOARSE; i += 256) sa[i] = as_[i];
    __syncthreads();
    int lane = t & 63, wv = t >> 6;
    int j = blockIdx.x * 4 + wv;
    float arj = ar_[j];
    float m = -INFINITY;
    for (int i = 0; i < NCOARSE; i++) {
        if (cnt[i * NCOARSE + j]) m = fmaxf(m, lrelu(sa[i] + arj));
    }
    float ss = 0.f, acc = 0.f;
    for (int i = 0; i < NCOARSE; i++) {
        unsigned c = cnt[i * NCOARSE + j];
        if (c) {
            float w = (float)c * __expf(lrelu(sa[i] + arj) - m);
            ss += w;
            acc += w * h[i * 64 + lane];
        }
    }
    g[j * 64 + lane] = ss > 0.f ? acc / ss : 0.f;
}

// ---- coarse graphnorm + silu + residual (wave per feature) ----
__global__ __launch_bounds__(64) void k_cnorm(const float* __restrict__ gin, const float* __restrict__ gamma,
                                              const float* __restrict__ beta, const float* __restrict__ res,
                                              float* __restrict__ xout) {
    int f = blockIdx.x, lane = threadIdx.x;
    float v[8];
    float s = 0.f, q = 0.f;
#pragma unroll
    for (int k = 0; k < 8; k++) {
        v[k] = gin[(lane + 64 * k) * 64 + f];
        s += v[k];
        q += v[k] * v[k];
    }
#pragma unroll
    for (int off = 32; off; off >>= 1) {
        s += __shfl_down(s, off);
        q += __shfl_down(q, off);
    }
    s = __shfl(s, 0);
    q = __shfl(q, 0);
    float mean = s / 512.f, var = q / 512.f - mean * mean, rstd = rsqrtf(var + 1e-5f);
    float gf = gamma[f], bf = beta[f];
#pragma unroll
    for (int k = 0; k < 8; k++) {
        float y = gf * (v[k] - mean) * rstd + bf;
        float si = y / (1.f + __expf(-y));
        int idx = (lane + 64 * k) * 64 + f;
        xout[idx] = si + res[idx];
    }
}

// ---- final: out = sum_n sum_f (g3+x3)[n][f] * dW[f] + db ----
__global__ __launch_bounds__(256) void k_final(const float* __restrict__ g3, const float* __restrict__ x3,
                                               const float* __restrict__ dW, const float* __restrict__ db,
                                               float* __restrict__ out) {
    __shared__ float l[4];
    int t = threadIdx.x;
    float p = 0.f;
    for (int idx = t; idx < NCOARSE * 64; idx += 256) p += (g3[idx] + x3[idx]) * dW[idx & 63];
#pragma unroll
    for (int off = 32; off; off >>= 1) p += __shfl_down(p, off);
    if ((t & 63) == 0) l[t >> 6] = p;
    __syncthreads();
    if (t == 0) out[0] = l[0] + l[1] + l[2] + l[3] + db[0];
}

extern "C" void kernel_launch(void* const* d_in, const int* in_sizes, int n_in,
                              void* d_out, int out_size, void* d_ws, size_t ws_size,
                              hipStream_t stream) {
    const float* nodes = (const float*)d_in[0];
    const int* senders = (const int*)d_in[1];
    const int* receivers = (const int*)d_in[2];
    const int* bnodes = (const int*)d_in[3];
    const float* dmean = (const float*)d_in[4];
    const float* dstd = (const float*)d_in[5];
    const float* eW = (const float*)d_in[6];
    const float* eb = (const float*)d_in[7];
    const float* W1 = (const float*)d_in[8];
    const float* A1 = (const float*)d_in[9];
    const float* gamma1 = (const float*)d_in[10];
    const float* beta1 = (const float*)d_in[11];
    const float* W2 = (const float*)d_in[12];
    const float* A2 = (const float*)d_in[13];
    const float* gamma2 = (const float*)d_in[14];
    const float* beta2 = (const float*)d_in[15];
    const float* W3 = (const float*)d_in[16];
    const float* A3 = (const float*)d_in[17];
    const float* dW = (const float*)d_in[18];
    const float* db = (const float*)d_in[19];
    float* out = (float*)d_out;

    char* p = (char*)d_ws;
    auto alloc = [&](size_t b) { char* r = p; p += (b + 255) & ~(size_t)255; return r; };
    float* x_emb = (float*)alloc((size_t)NN * 64 * 4);   // res1
    float* h1 = (float*)alloc((size_t)NN * 64 * 4);      // reused as x1 after gat1
    float* o_raw = (float*)alloc((size_t)NN * 64 * 4);
    float* as1 = (float*)alloc(NN * 4);
    float* ar1 = (float*)alloc(NN * 4);
    int* bid = (int*)alloc(NN * 4);
    unsigned char* isb = (unsigned char*)alloc(NN);
    float* colsum = (float*)alloc(64 * 4);
    float* colsq = (float*)alloc(64 * 4);
    float* mr = (float*)alloc(128 * 4);
    unsigned* mn_ord = (unsigned*)alloc(3 * 4);
    unsigned* mx_ord = (unsigned*)alloc(3 * 4);
    unsigned* cnt = (unsigned*)alloc((size_t)NCOARSE * NCOARSE * 4);
    float* cn = (float*)alloc(NCOARSE * 64 * 4);
    float* bsize = (float*)alloc(NCOARSE * 4);
    float* x2 = (float*)alloc(NCOARSE * 64 * 4);   // res2
    float* h2 = (float*)alloc(NCOARSE * 64 * 4);
    float* as2 = (float*)alloc(NCOARSE * 4);
    float* ar2 = (float*)alloc(NCOARSE * 4);
    float* gat2 = (float*)alloc(NCOARSE * 64 * 4);
    float* x3 = (float*)alloc(NCOARSE * 64 * 4);   // res3
    float* h3 = (float*)alloc(NCOARSE * 64 * 4);
    float* as3 = (float*)alloc(NCOARSE * 4);
    float* ar3 = (float*)alloc(NCOARSE * 4);
    float* gat3 = (float*)alloc(NCOARSE * 64 * 4);
    unsigned* deg = (unsigned*)alloc(NN * 4);
    unsigned* rowptr = (unsigned*)alloc((NN + 1) * 4);
    unsigned* cursor = (unsigned*)alloc(NN * 4);
    unsigned* partial = (unsigned*)alloc(512 * 4);
    int* csr_s = (int*)alloc((size_t)NE * 4);

    hipMemsetAsync(isb, 0, NN, stream);
    hipMemsetAsync(colsum, 0, 64 * 4, stream);
    hipMemsetAsync(colsq, 0, 64 * 4, stream);
    hipMemsetAsync(mn_ord, 0xFF, 12, stream);
    hipMemsetAsync(mx_ord, 0, 12, stream);
    hipMemsetAsync(cnt, 0, (size_t)NCOARSE * NCOARSE * 4, stream);
    hipMemsetAsync(cn, 0, NCOARSE * 64 * 4, stream);
    hipMemsetAsync(bsize, 0, NCOARSE * 4, stream);
    hipMemsetAsync(deg, 0, NN * 4, stream);

    k_scatter<<<(NBN + 255) / 256, 256, 0, stream>>>(bnodes, isb);
    k_embed<<<2048, 256, 0, stream>>>(nodes, isb, dmean, dstd, eW, eb, x_emb);
    k_minmax<<<512, 256, 0, stream>>>(nodes, mn_ord, mx_ord);
    k_bid<<<(NN + 255) / 256, 256, 0, stream>>>(nodes, mn_ord, mx_ord, bid);
    k_deg<<<(NE + 255) / 256, 256, 0, stream>>>(receivers, deg);
    k_scan1<<<NSB, 256, 0, stream>>>(deg, rowptr, partial);
    k_scan2<<<1, 512, 0, stream>>>(partial);
    k_scan3<<<NSB, 256, 0, stream>>>(rowptr, partial, cursor);
    k_fill<<<(NE + 255) / 256, 256, 0, stream>>>(senders, receivers, cursor, csr_s);
    k_mm<<<2048, 256, 0, stream>>>(x_emb, W1, A1, h1, as1, ar1, NN);
    k_gat1<<<NN / 4, 256, 0, stream>>>(rowptr, csr_s, as1, ar1, h1, o_raw);
    k_stats2<<<512, 256, 0, stream>>>(o_raw, colsum, colsq);
    k_meanvar<<<1, 64, 0, stream>>>(colsum, colsq, mr);
    k_apply<<<NN / 4, 256, 0, stream>>>(o_raw, x_emb, gamma1, beta1, mr, bid, h1, cn, bsize);
    k_cnt<<<(NE + 255) / 256, 256, 0, stream>>>(senders, receivers, bid, cnt);
    k_cnscale<<<NCOARSE / 4, 256, 0, stream>>>(cn, bsize, x2);
    k_mm<<<NCOARSE / 4, 256, 0, stream>>>(x2, W2, A2, h2, as2, ar2, NCOARSE);
    k_cgat<<<NCOARSE / 4, 256, 0, stream>>>(h2, as2, ar2, cnt, gat2);
    k_cnorm<<<64, 64, 0, stream>>>(gat2, gamma2, beta2, x2, x3);
    k_mm<<<NCOARSE / 4, 256, 0, stream>>>(x3, W3, A3, h3, as3, ar3, NCOARSE);
    k_cgat<<<NCOARSE / 4, 256, 0, stream>>>(h3, as3, ar3, cnt, gat3);
    k_final<<<1, 256, 0, stream>>>(gat3, x3, dW, db, out);
}